// Round 1
// baseline (951.191 us; speedup 1.0000x reference)
//
#include <hip/hip_runtime.h>

#define VN 50000
#define RN 5
#define AN 8
#define CN 32
#define TN 32
#define NROT 4
#define NTOT 128    // NROT*TN
#define KTOT 1280   // RN*AN*CN
#define KC 256      // per-r chunk = AN*CN
#define DELTA_ 2

// Build rotated-template matrices: B[k][nt], k=(r*A+a)*C+c, nt=n*T+t
// B[k][nt] = templ[t, r, (a - n*DELTA) mod A, c]
__global__ void build_B(const float* __restrict__ t1, const float* __restrict__ t2,
                        float* __restrict__ B1, float* __restrict__ B2) {
    int m = blockIdx.x * blockDim.x + threadIdx.x;
    if (m >= KTOT * NTOT) return;
    int k = m / NTOT, nt = m % NTOT;
    int r = k / (AN * CN), a = (k / CN) % AN, c = k % CN;
    int n = nt / TN, t = nt % TN;
    int asrc = (a - n * DELTA_ + AN) % AN;   // n*DELTA <= 6 < 8, stays positive
    int src = ((t * RN + r) * AN + asrc) * CN + c;
    B1[m] = t1[src];
    B2[m] = t2[src];
}

// One conv + AngularMaxPool (+bias, +optional residual, +relu).
// Block: 128 threads handles 32 vertices x 128 (n,t) outputs.
// Register tile per thread: 4 vertices x 8 outputs.
template<bool FIRST>
__global__ __launch_bounds__(128)
void conv_amp(const float* __restrict__ x,        // [V][32] conv input
              const int*   __restrict__ bc_idx,   // [V][R][A][3]
              const float* __restrict__ bc_w,     // [V][R][A][3]
              const float* __restrict__ Bm,       // [KTOT][NTOT]
              const float* __restrict__ bias,     // [T]
              const float* __restrict__ signal,   // [V][32] residual (conv2)
              float* __restrict__ out) {          // [V][32]
    __shared__ float interp_s[32][258];           // pad 258: v-stride%32 benign
    __shared__ float b_s[32][128];

    const int tid = threadIdx.x;
    const int v0 = blockIdx.x * 32;
    const int ty = tid >> 4;    // 0..7 -> vertex group of 4
    const int tx = tid & 15;    // 0..15 -> 8 consecutive nt outputs

    float acc[4][8];
#pragma unroll
    for (int i = 0; i < 4; ++i)
#pragma unroll
        for (int j = 0; j < 8; ++j) acc[i][j] = 0.f;

    const float4* x4 = (const float4*)x;          // rows of 8 float4

    for (int r = 0; r < RN; ++r) {
        // ---- phase A: barycentric interp for this r -> LDS [32 v][256 k] ----
#pragma unroll
        for (int p = 0; p < 2; ++p) {
            int pid = tid + p * 128;              // 0..255 -> (v,a)
            int vl = pid >> 3, a = pid & 7;
            int vg = v0 + vl;
            float w0 = 0.f, w1 = 0.f, w2 = 0.f;
            int i0 = 0, i1 = 0, i2 = 0;
            if (vg < VN) {
                int base = ((vg * RN + r) * AN + a) * 3;
                i0 = bc_idx[base + 0]; i1 = bc_idx[base + 1]; i2 = bc_idx[base + 2];
                w0 = bc_w[base + 0];  w1 = bc_w[base + 1];  w2 = bc_w[base + 2];
            }
            float4* dst = (float4*)&interp_s[vl][a * CN];
#pragma unroll
            for (int j = 0; j < 8; ++j) {
                float4 g0 = x4[i0 * 8 + j];
                float4 g1 = x4[i1 * 8 + j];
                float4 g2 = x4[i2 * 8 + j];
                float4 o;
                o.x = w0 * g0.x + w1 * g1.x + w2 * g2.x;
                o.y = w0 * g0.y + w1 * g1.y + w2 * g2.y;
                o.z = w0 * g0.z + w1 * g1.z + w2 * g2.z;
                o.w = w0 * g0.w + w1 * g1.w + w2 * g2.w;
                dst[j] = o;
            }
        }
        __syncthreads();

        // ---- phase B: GEMM over this r's 256 k, sub-chunks of 32 ----
        const float* Bbase = Bm + (size_t)r * KC * NTOT;
        for (int sub = 0; sub < 8; ++sub) {
            const float4* Bg = (const float4*)(Bbase + sub * 32 * NTOT);
            float4* bs4 = (float4*)&b_s[0][0];
#pragma unroll
            for (int j = 0; j < 8; ++j)
                bs4[j * 128 + tid] = Bg[j * 128 + tid];   // coalesced L2 read
            __syncthreads();
#pragma unroll
            for (int kk = 0; kk < 32; ++kk) {
                float av[4];
#pragma unroll
                for (int i = 0; i < 4; ++i)
                    av[i] = interp_s[ty * 4 + i][sub * 32 + kk];
                float4 b0 = *(const float4*)&b_s[kk][tx * 8];
                float4 b1 = *(const float4*)&b_s[kk][tx * 8 + 4];
#pragma unroll
                for (int i = 0; i < 4; ++i) {
                    acc[i][0] = fmaf(av[i], b0.x, acc[i][0]);
                    acc[i][1] = fmaf(av[i], b0.y, acc[i][1]);
                    acc[i][2] = fmaf(av[i], b0.z, acc[i][2]);
                    acc[i][3] = fmaf(av[i], b0.w, acc[i][3]);
                    acc[i][4] = fmaf(av[i], b1.x, acc[i][4]);
                    acc[i][5] = fmaf(av[i], b1.y, acc[i][5]);
                    acc[i][6] = fmaf(av[i], b1.z, acc[i][6]);
                    acc[i][7] = fmaf(av[i], b1.w, acc[i][7]);
                }
            }
            __syncthreads();
        }
    }

    // ---- epilogue: AngularMaxPool over n, then bias(+residual)+relu ----
    // nt = tx*8 + j ; t = nt % 32 = (tx&3)*8+j ; n = nt/32 = tx>>2.
    // Lanes tx, tx^4, tx^8 hold the other n's for the same t.
#pragma unroll
    for (int i = 0; i < 4; ++i) {
        int vg = v0 + ty * 4 + i;
#pragma unroll
        for (int j = 0; j < 8; ++j) {
            float m = acc[i][j];
            m = fmaxf(m, __shfl_xor(m, 4));
            m = fmaxf(m, __shfl_xor(m, 8));
            if ((tx & 12) == 0 && vg < VN) {
                int t = (tx & 3) * 8 + j;
                float val = m + bias[t];
                if (!FIRST) val += signal[vg * CN + t];
                out[vg * CN + t] = fmaxf(val, 0.f);
            }
        }
    }
}

extern "C" void kernel_launch(void* const* d_in, const int* in_sizes, int n_in,
                              void* d_out, int out_size, void* d_ws, size_t ws_size,
                              hipStream_t stream) {
    const float* signal = (const float*)d_in[0];
    const int*   bc_idx = (const int*)d_in[1];
    const float* bc_w   = (const float*)d_in[2];
    const float* t1     = (const float*)d_in[3];
    const float* b1     = (const float*)d_in[4];
    const float* t2     = (const float*)d_in[5];
    const float* b2     = (const float*)d_in[6];
    float* out = (float*)d_out;

    float* ws = (float*)d_ws;
    float* B1 = ws;                          // 163840 f32
    float* B2 = ws + KTOT * NTOT;            // 163840 f32
    float* s1 = ws + 2 * KTOT * NTOT;        // 1.6M f32
    // total workspace use: 7.71 MB

    build_B<<<(KTOT * NTOT + 255) / 256, 256, 0, stream>>>(t1, t2, B1, B2);

    int blocks = (VN + 31) / 32;
    conv_amp<true ><<<blocks, 128, 0, stream>>>(signal, bc_idx, bc_w, B1, b1, signal, s1);
    conv_amp<false><<<blocks, 128, 0, stream>>>(s1,     bc_idx, bc_w, B2, b2, signal, out);
}

// Round 2
// 221.515 us; speedup vs baseline: 4.2940x; 4.2940x over previous
//
#include <hip/hip_runtime.h>
#include <hip/hip_bf16.h>

#define VN 50000
#define RN 5
#define AN 8
#define CN 32
#define TN 32
#define KSTEPS 40   // RN*AN; one kstep == one (r,a), K=32 channels
#define NB 8        // N-blocks of 16 (NTOT = 128 = n_rot*T)

typedef __attribute__((ext_vector_type(8))) short bf16x8;
typedef __attribute__((ext_vector_type(4))) float f32x4;

__device__ __forceinline__ float b2f(short s) {
    union { unsigned u; float f; } cv;
    cv.u = ((unsigned)(unsigned short)s) << 16;
    return cv.f;
}
__device__ __forceinline__ short f2b(float f) {
    union { float f; unsigned u; } cv; cv.f = f;
    unsigned r = cv.u + 0x7fff + ((cv.u >> 16) & 1);   // RNE
    return (short)(r >> 16);
}

// f32 -> bf16 pack of the conv-1 input signal
__global__ void pack_x(const float* __restrict__ x, __hip_bfloat16* __restrict__ xb, int n4) {
    int i = blockIdx.x * blockDim.x + threadIdx.x;
    if (i >= n4) return;
    float4 v = ((const float4*)x)[i];
    ushort4 o;
    o.x = (unsigned short)f2b(v.x);
    o.y = (unsigned short)f2b(v.y);
    o.z = (unsigned short)f2b(v.z);
    o.w = (unsigned short)f2b(v.w);
    ((ushort4*)xb)[i] = o;
}

// Rolled templates -> MFMA-fragment-order bf16 matrices.
// Bp flat index = ((kstep*NB + nb)*64 + lane)*8 + j
// value = templ[t, r, (a - 2n) mod 8, c], k=(r*8+a)*32+c, nt=nb*16+(lane&15)
__global__ void build_Bp(const float* __restrict__ t1, const float* __restrict__ t2,
                         __hip_bfloat16* __restrict__ B1, __hip_bfloat16* __restrict__ B2) {
    int m = blockIdx.x * blockDim.x + threadIdx.x;
    if (m >= KSTEPS * NB * 64 * 8) return;
    int j = m & 7;
    int lane = (m >> 3) & 63;
    int nb = (m >> 9) & 7;
    int kstep = m >> 12;
    int c = ((lane >> 4) << 3) + j;
    int r = kstep >> 3, a = kstep & 7;
    int nt = nb * 16 + (lane & 15);
    int n = nt >> 5, t = nt & 31;
    int asrc = (a - 2 * n + 8) & 7;
    int src = ((t * RN + r) * AN + asrc) * CN + c;
    B1[m] = __hip_bfloat16(); ((unsigned short*)B1)[m] = (unsigned short)f2b(t1[src]);
    ((unsigned short*)B2)[m] = (unsigned short)f2b(t2[src]);
}

__device__ __forceinline__ bf16x8 gather_blend(const __hip_bfloat16* __restrict__ xb,
                                               const int* __restrict__ ip,
                                               const float* __restrict__ wp, int c0) {
    int i0 = ip[0], i1 = ip[1], i2 = ip[2];
    float w0 = wp[0], w1 = wp[1], w2 = wp[2];
    bf16x8 g0 = *(const bf16x8*)((const unsigned short*)xb + i0 * CN + c0);
    bf16x8 g1 = *(const bf16x8*)((const unsigned short*)xb + i1 * CN + c0);
    bf16x8 g2 = *(const bf16x8*)((const unsigned short*)xb + i2 * CN + c0);
    bf16x8 o;
#pragma unroll
    for (int j = 0; j < 8; ++j) {
        float f = fmaf(w0, b2f(g0[j]), fmaf(w1, b2f(g1[j]), w2 * b2f(g2[j])));
        o[j] = f2b(f);
    }
    return o;
}

// Fused gather + interp + GEMM + AngularMaxPool (+bias/residual/relu).
// 2 waves/block, each wave: 32 vertices x 128 (n,t). No LDS, no syncs.
template<bool FIRST>
__global__ __launch_bounds__(128)
void conv_mfma(const __hip_bfloat16* __restrict__ xb,   // [V][32] bf16 input
               const int*   __restrict__ bc_idx,        // [V][120]
               const float* __restrict__ bc_w,          // [V][120]
               const __hip_bfloat16* __restrict__ Bp,   // fragment layout
               const float* __restrict__ bias,          // [32]
               const float* __restrict__ signal,        // residual f32 (conv2)
               __hip_bfloat16* __restrict__ out_bf,     // conv1 out (s1, bf16)
               float* __restrict__ out_f)               // conv2 out (f32)
{
    const int tid = threadIdx.x;
    const int wid = tid >> 6;
    const int lane = tid & 63;
    const int vbase = (blockIdx.x * 2 + wid) * 32;

    const int arow = lane & 15;          // A-fragment row
    const int c0 = (lane >> 4) << 3;     // channel sub-offset (8 contiguous k)

    int v0 = vbase + arow;
    int v1 = v0 + 16;
    int vc0 = v0 < VN ? v0 : VN - 1;
    int vc1 = v1 < VN ? v1 : VN - 1;

    const int* ip0 = bc_idx + vc0 * 120;
    const int* ip1 = bc_idx + vc1 * 120;
    const float* wp0 = bc_w + vc0 * 120;
    const float* wp1 = bc_w + vc1 * 120;
    const bf16x8* Bfrag = (const bf16x8*)Bp + lane;   // + (ks*NB+nb)*64

    f32x4 acc[2][NB];
#pragma unroll
    for (int mi = 0; mi < 2; ++mi)
#pragma unroll
        for (int nb = 0; nb < NB; ++nb) acc[mi][nb] = (f32x4)(0.f);

#pragma unroll 2
    for (int ks = 0; ks < KSTEPS; ++ks) {
        bf16x8 afrag0 = gather_blend(xb, ip0, wp0, c0);
        bf16x8 afrag1 = gather_blend(xb, ip1, wp1, c0);
        ip0 += 3; ip1 += 3; wp0 += 3; wp1 += 3;
#pragma unroll
        for (int nb = 0; nb < NB; ++nb) {
            bf16x8 bfrag = Bfrag[(ks * NB + nb) * 64];
            acc[0][nb] = __builtin_amdgcn_mfma_f32_16x16x32_bf16(afrag0, bfrag, acc[0][nb], 0, 0, 0);
            acc[1][nb] = __builtin_amdgcn_mfma_f32_16x16x32_bf16(afrag1, bfrag, acc[1][nb], 0, 0, 0);
        }
    }

    // Epilogue: AMP over n (register-local: nb parity q = t-half, nb>>1 = n),
    // then bias (+residual) + relu + store.
    const int colD = lane & 15;             // t within half
    const int rbase = (lane >> 4) << 2;     // D row base
#pragma unroll
    for (int mi = 0; mi < 2; ++mi) {
#pragma unroll
        for (int q = 0; q < 2; ++q) {
            f32x4 mx;
#pragma unroll
            for (int rg = 0; rg < 4; ++rg)
                mx[rg] = fmaxf(fmaxf(acc[mi][q][rg], acc[mi][q + 2][rg]),
                               fmaxf(acc[mi][q + 4][rg], acc[mi][q + 6][rg]));
            int t = q * 16 + colD;
            float b = bias[t];
#pragma unroll
            for (int rg = 0; rg < 4; ++rg) {
                int v = vbase + mi * 16 + rbase + rg;
                if (v < VN) {
                    float val = mx[rg] + b;
                    if (FIRST) {
                        ((unsigned short*)out_bf)[v * CN + t] =
                            (unsigned short)f2b(fmaxf(val, 0.f));
                    } else {
                        val += signal[v * CN + t];
                        out_f[v * CN + t] = fmaxf(val, 0.f);
                    }
                }
            }
        }
    }
}

extern "C" void kernel_launch(void* const* d_in, const int* in_sizes, int n_in,
                              void* d_out, int out_size, void* d_ws, size_t ws_size,
                              hipStream_t stream) {
    const float* signal = (const float*)d_in[0];
    const int*   bc_idx = (const int*)d_in[1];
    const float* bc_w   = (const float*)d_in[2];
    const float* t1     = (const float*)d_in[3];
    const float* b1     = (const float*)d_in[4];
    const float* t2     = (const float*)d_in[5];
    const float* b2     = (const float*)d_in[6];
    float* out = (float*)d_out;

    __hip_bfloat16* ws = (__hip_bfloat16*)d_ws;
    __hip_bfloat16* xb  = ws;                       // V*32 bf16 = 1.6M elems
    __hip_bfloat16* s1  = ws + VN * CN;             // V*32 bf16
    __hip_bfloat16* Bp1 = ws + 2 * VN * CN;         // 163840 bf16
    __hip_bfloat16* Bp2 = Bp1 + KSTEPS * NB * 64 * 8;
    // total ws use: (3.2M + 327K) elems * 2B ~= 7.0 MB

    pack_x<<<(VN * CN / 4 + 255) / 256, 256, 0, stream>>>(signal, xb, VN * CN / 4);
    build_Bp<<<(KSTEPS * NB * 64 * 8) / 256, 256, 0, stream>>>(t1, t2, Bp1, Bp2);

    int blocks = (VN + 63) / 64;   // 2 waves/block, 32 v/wave
    conv_mfma<true ><<<blocks, 128, 0, stream>>>(xb, bc_idx, bc_w, Bp1, b1, nullptr, s1, nullptr);
    conv_mfma<false><<<blocks, 128, 0, stream>>>(s1, bc_idx, bc_w, Bp2, b2, signal, nullptr, out);
}